// Round 3
// baseline (103.365 us; speedup 1.0000x reference)
//
#include <hip/hip_runtime.h>

// DIAGNOSTIC ROUND: kernel body identical to Round 2. kernel_launch enqueues
// ringnn_fused THREE times (idempotent: same inputs -> same output written
// three times, stream-serialized). Purpose: measure the main kernel's true
// duration, which the top-5 profile hides behind the 40 us poison fills:
//   main_dur ~= (dur_this_round - dur_round2) / 2  - node overhead.
// Branch rule: <9 us -> harness-floor roofline; >15 us -> optimize internals.
//
// LDS/block: cs1 6272 + cs2 2304 + b2t 4096 + fft 11520 + w1t 128 = 24320 B.

typedef _Float16 h2  __attribute__((ext_vector_type(2)));
typedef _Float16 v8h __attribute__((ext_vector_type(8)));
typedef float    f4  __attribute__((ext_vector_type(4)));

__device__ __forceinline__ float fdot2(unsigned a, unsigned b, float c) {
    return __builtin_amdgcn_fdot2(__builtin_bit_cast(h2, a),
                                  __builtin_bit_cast(h2, b), c, false);
}
__device__ __forceinline__ unsigned packh2(float x, float y) {
    h2 h; h.x = (_Float16)x; h.y = (_Float16)y;
    return __builtin_bit_cast(unsigned, h);
}
// (c,s) -> (-s,c): rotate 16 then flip f16 sign bit of the low half.
__device__ __forceinline__ unsigned yrot(unsigned u) {
    return __builtin_amdgcn_alignbit(u, u, 16) ^ 0x8000u;
}

__global__ __launch_bounds__(256) void ringnn_fused(
    const float* __restrict__ x,
    const float* __restrict__ w1,
    const float* __restrict__ w2,
    const float* __restrict__ ffw,
    float* __restrict__ out)
{
    __shared__ __align__(16) unsigned cs1[2][784];  // [img][c*196+i*14+j], h2
    __shared__ __align__(16) unsigned cs2[2][288];  // [img][(i*6+j)*8+o], h2
    __shared__ __align__(16) uint4    b2t[256];     // conv2 MFMA B-fragments
    __shared__ __align__(16) unsigned fft[2880];    // ff (cos,sin), [f*10+n]
    __shared__ uint2 w1t[16];                       // conv1 (X-wt, Y-wt)

    const int t    = threadIdx.x;
    const int wave = t >> 6;               // 0..3
    const int lane = t & 63;
    const int img  = t >> 7;               // 0..1 (stage 3)
    const int b0   = blockIdx.x * 2;

    // ---- Stage-1 global loads issued FIRST (latency hides the table build).
    const int imA = (t >= 196) ? 1 : 0;
    const int pA  = t - imA * 196;
    const int iA  = pA / 14, jA = pA - iA * 14;
    const float* pxA = x + (b0 + imA) * 784 + (2 * iA) * 28 + 2 * jA;
    const float2 rA0 = *(const float2*)(pxA);
    const float2 rA1 = *(const float2*)(pxA + 28);

    const bool hasB = (t < 136);
    const int pB  = t + 60;                // (t+256)-196, always img 1
    const int iB  = pB / 14, jB = pB - iB * 14;
    const float* pxB = x + (b0 + 1) * 784 + (2 * iB) * 28 + 2 * jB;
    float2 rB0 = {0.f, 0.f}, rB1 = {0.f, 0.f};
    if (hasB) { rB0 = *(const float2*)(pxB); rB1 = *(const float2*)(pxB + 28); }

    // ---- Per-block weight tables (VALU, overlaps the x loads) ----
    if (t < 16) {
        float s, c;
        __sincosf(w1[t], &s, &c);
        w1t[t] = make_uint2(packh2(c, s), packh2(-s, c));
    }
    {   // conv2 B-fragment entry e = (c*4+dy)*16 + n, one per thread
        const int nn = t & 15;
        const int dy = (t >> 4) & 3;
        const int cc = t >> 6;
        const int o  = nn >> 1;
        unsigned d[4];
        #pragma unroll
        for (int dx = 0; dx < 4; ++dx) {
            float a = w2[o * 64 + cc * 16 + dy * 4 + dx];
            float ss, cw;
            __sincosf(a, &ss, &cw);
            d[dx] = (nn & 1) ? packh2(-ss, cw) : packh2(cw, ss);
        }
        b2t[t] = make_uint4(d[0], d[1], d[2], d[3]);
    }
    for (int e = t; e < 2880; e += 256) {   // ff: 11.25 entries/thread
        float ss, cw;
        __sincosf(ffw[e], &ss, &cw);
        fft[e] = packh2(cw, ss);
    }
    __syncthreads();

    const int n    = lane & 15;
    const int quad = lane >> 4;
    uint4 bf0 = b2t[lane];
    uint4 bf1 = b2t[64 + lane];
    uint4 bf2 = b2t[128 + lane];
    uint4 bf3 = b2t[192 + lane];

    // ---- Stage 1: sincos + 2x2/s2 conv, 1->4 ch ----
    {
        float s0, c0, s1, c1, s2, c2, s3, c3;
        __sincosf(rA0.x, &s0, &c0);
        __sincosf(rA0.y, &s1, &c1);
        __sincosf(rA1.x, &s2, &c2);
        __sincosf(rA1.y, &s3, &c3);
        const unsigned u0 = packh2(c0, s0), u1 = packh2(c1, s1);
        const unsigned u2 = packh2(c2, s2), u3 = packh2(c3, s3);
        #pragma unroll
        for (int o = 0; o < 4; ++o) {
            const uint2 wa = w1t[o * 4 + 0], wb = w1t[o * 4 + 1];
            const uint2 wc = w1t[o * 4 + 2], wd = w1t[o * 4 + 3];
            float X = 0.f, Y = 0.f;
            X = fdot2(u0, wa.x, X); Y = fdot2(u0, wa.y, Y);
            X = fdot2(u1, wb.x, X); Y = fdot2(u1, wb.y, Y);
            X = fdot2(u2, wc.x, X); Y = fdot2(u2, wc.y, Y);
            X = fdot2(u3, wd.x, X); Y = fdot2(u3, wd.y, Y);
            const float rinv = rsqrtf(fmaxf(fmaf(X, X, Y * Y), 1e-30f));
            cs1[imA][o * 196 + pA] = packh2(X * rinv, Y * rinv);
        }
    }
    if (hasB) {
        float s0, c0, s1, c1, s2, c2, s3, c3;
        __sincosf(rB0.x, &s0, &c0);
        __sincosf(rB0.y, &s1, &c1);
        __sincosf(rB1.x, &s2, &c2);
        __sincosf(rB1.y, &s3, &c3);
        const unsigned u0 = packh2(c0, s0), u1 = packh2(c1, s1);
        const unsigned u2 = packh2(c2, s2), u3 = packh2(c3, s3);
        #pragma unroll
        for (int o = 0; o < 4; ++o) {
            const uint2 wa = w1t[o * 4 + 0], wb = w1t[o * 4 + 1];
            const uint2 wc = w1t[o * 4 + 2], wd = w1t[o * 4 + 3];
            float X = 0.f, Y = 0.f;
            X = fdot2(u0, wa.x, X); Y = fdot2(u0, wa.y, Y);
            X = fdot2(u1, wb.x, X); Y = fdot2(u1, wb.y, Y);
            X = fdot2(u2, wc.x, X); Y = fdot2(u2, wc.y, Y);
            X = fdot2(u3, wd.x, X); Y = fdot2(u3, wd.y, Y);
            const float rinv = rsqrtf(fmaxf(fmaf(X, X, Y * Y), 1e-30f));
            cs1[1][o * 196 + pB] = packh2(X * rinv, Y * rinv);
        }
    }
    __syncthreads();

    // ---- Stage 2: MFMA. 72 positions (2 images x 36) = 5 tiles of 16 ----
    const unsigned* c1 = &cs1[0][0];
    for (int tile = wave; tile < 5; tile += 4) {
        const int p  = tile * 16 + n;
        const int pc = (p < 72) ? p : 71;          // clamp pad lanes (tile 4)
        const int im = (pc >= 36) ? 1 : 0;
        const int ps = pc - im * 36;
        const int i  = ps / 6;
        const int j  = ps - i * 6;
        const unsigned base = (unsigned)(im * 784 + (2 * i + quad) * 14 + 2 * j);
        f4 acc = {0.f, 0.f, 0.f, 0.f};
        #pragma unroll
        for (int c = 0; c < 4; ++c) {
            uint2 lo = *(const uint2*)(c1 + base + c * 196);
            uint2 hi = *(const uint2*)(c1 + base + c * 196 + 2);
            uint4 a4 = make_uint4(lo.x, lo.y, hi.x, hi.y);
            v8h av = __builtin_bit_cast(v8h, a4);
            v8h bv = __builtin_bit_cast(v8h, (c == 0) ? bf0 : (c == 1) ? bf1
                                              : (c == 2) ? bf2 : bf3);
            acc = __builtin_amdgcn_mfma_f32_16x16x32_f16(av, bv, acc, 0, 0, 0);
        }
        float pr0 = __shfl_xor(acc[0], 1);
        float pr1 = __shfl_xor(acc[1], 1);
        float pr2 = __shfl_xor(acc[2], 1);
        float pr3 = __shfl_xor(acc[3], 1);
        if (!(n & 1)) {
            const int o = n >> 1;
            float Xs[4] = {acc[0], acc[1], acc[2], acc[3]};
            float Ys[4] = {pr0, pr1, pr2, pr3};
            #pragma unroll
            for (int r = 0; r < 4; ++r) {
                const int p2 = tile * 16 + quad * 4 + r;
                if (p2 < 72) {
                    const int im2 = (p2 >= 36) ? 1 : 0;
                    const int ps2 = p2 - im2 * 36;
                    float X = Xs[r], Y = Ys[r];
                    float rinv = rsqrtf(fmaxf(fmaf(X, X, Y * Y), 1e-30f));
                    cs2[im2][ps2 * 8 + o] = packh2(X * rinv, Y * rinv);
                }
            }
        }
    }
    __syncthreads();

    // ---- Stage 3: ring-FF 288 -> 10; two independent 12-iter chains ----
    {
        const int half = wave & 1;
        const int nl   = lane / 12;              // 0..4 active
        const int g    = lane - nl * 12;
        float XA = 0.f, YA = 0.f, XB = 0.f, YB = 0.f;
        if (nl < 5) {
            const int n3 = half * 5 + nl;
            #pragma unroll 6
            for (int k = 0; k < 12; ++k) {
                const int fA = g + 12 * k;       // features 0..143
                const int fB = fA + 144;         // features 144..287
                unsigned va = cs2[img][fA];
                unsigned vb = cs2[img][fB];
                unsigned ua = fft[fA * 10 + n3];
                unsigned ub = fft[fB * 10 + n3];
                XA = fdot2(va, ua, XA);
                YA = fdot2(va, yrot(ua), YA);
                XB = fdot2(vb, ub, XB);
                YB = fdot2(vb, yrot(ub), YB);
            }
        }
        float X = XA + XB, Y = YA + YB;
        float qX = X + __shfl_down(X, 4) + __shfl_down(X, 8);
        float qY = Y + __shfl_down(Y, 4) + __shfl_down(Y, 8);
        float sX = qX + __shfl_down(qX, 1) + __shfl_down(qX, 2) + __shfl_down(qX, 3);
        float sY = qY + __shfl_down(qY, 1) + __shfl_down(qY, 2) + __shfl_down(qY, 3);
        if (g == 0 && nl < 5) {
            const int n3 = half * 5 + nl;
            float rinv = rsqrtf(fmaxf(fmaf(sX, sX, sY * sY), 1e-30f));
            out[(b0 + img) * 10 + n3] = sY * rinv;
        }
    }
}

extern "C" void kernel_launch(void* const* d_in, const int* in_sizes, int n_in,
                              void* d_out, int out_size, void* d_ws, size_t ws_size,
                              hipStream_t stream) {
    const float* x   = (const float*)d_in[0];
    const float* w1  = (const float*)d_in[1];
    const float* w2  = (const float*)d_in[2];
    const float* ffw = (const float*)d_in[3];
    (void)d_ws; (void)ws_size;
    // DIAGNOSTIC: 3 idempotent launches. dur_delta vs Round 2 = 2 x main_dur.
    ringnn_fused<<<2048, 256, 0, stream>>>(x, w1, w2, ffw, (float*)d_out);
    ringnn_fused<<<2048, 256, 0, stream>>>(x, w1, w2, ffw, (float*)d_out);
    ringnn_fused<<<2048, 256, 0, stream>>>(x, w1, w2, ffw, (float*)d_out);
}

// Round 4
// 73.232 us; speedup vs baseline: 1.4115x; 1.4115x over previous
//
#include <hip/hip_runtime.h>

// Fused kernel, 4 images per block / 512 threads (8 waves), grid 1024.
// vs Round 2 (2 imgs / 256 thr / grid 2048):
//  - ff table (2880 sincos) built once per 4 images (2x amortization),
//    and built AFTER stage 1 in the stage-2 region, aliased over the
//    consumed b2t fragment table (b2t is register-resident by then).
//  - LDS/block: cs1 12544 + cs2 4608 + fftb 11520 + w1t 128 = 28800 B.
//    Occupancy: wave-capped 4 blocks/CU = 32 waves/CU (hw max); grid 1024
//    = exactly one resident round, zero tail.
//  - Stage 2: 144 positions = 9 tiles of 16 exactly -> no clamp/guards.
// Stage 1/3 inner structure identical to the verified R2 kernel.

typedef _Float16 h2  __attribute__((ext_vector_type(2)));
typedef _Float16 v8h __attribute__((ext_vector_type(8)));
typedef float    f4  __attribute__((ext_vector_type(4)));

__device__ __forceinline__ float fdot2(unsigned a, unsigned b, float c) {
    return __builtin_amdgcn_fdot2(__builtin_bit_cast(h2, a),
                                  __builtin_bit_cast(h2, b), c, false);
}
__device__ __forceinline__ unsigned packh2(float x, float y) {
    h2 h; h.x = (_Float16)x; h.y = (_Float16)y;
    return __builtin_bit_cast(unsigned, h);
}
// (c,s) -> (-s,c): rotate 16 then flip f16 sign bit of the low half.
__device__ __forceinline__ unsigned yrot(unsigned u) {
    return __builtin_amdgcn_alignbit(u, u, 16) ^ 0x8000u;
}

__global__ __launch_bounds__(512) void ringnn_fused(
    const float* __restrict__ x,
    const float* __restrict__ w1,
    const float* __restrict__ w2,
    const float* __restrict__ ffw,
    float* __restrict__ out)
{
    __shared__ __align__(16) unsigned cs1[4][784];  // [img][c*196+i*14+j], h2
    __shared__ __align__(16) unsigned cs2[4][288];  // [img][(i*6+j)*8+o], h2
    // fftb: ff (cos,sin) [f*10+n], 2880 words. First 1024 words double as
    // b2t[256] (uint4 conv2 B-fragments): b2t is consumed into registers
    // before stage 1; fftb is written only after the stage-1 barrier.
    __shared__ __align__(16) unsigned fftb[2880];
    __shared__ uint2 w1t[16];                       // conv1 (X-wt, Y-wt)

    const int t    = threadIdx.x;          // 0..511
    const int wave = t >> 6;               // 0..7
    const int lane = t & 63;
    const int b0   = blockIdx.x * 4;

    // ---- Stage-1 global loads issued FIRST (latency hides the table build).
    // Position A: P = t (0..511). Position B: P = t + 512 (t < 272).
    const int pAi = t;
    const int imA = pAi / 196;             // 0..2
    const int pA  = pAi - imA * 196;
    const int iA  = pA / 14, jA = pA - iA * 14;
    const float* pxA = x + (b0 + imA) * 784 + (2 * iA) * 28 + 2 * jA;
    const float2 rA0 = *(const float2*)(pxA);
    const float2 rA1 = *(const float2*)(pxA + 28);

    const bool hasB = (t < 272);
    const int pBi = t + 512;               // 512..783
    const int imB = pBi / 196;             // 2..3
    const int pB  = pBi - imB * 196;
    const int iB  = pB / 14, jB = pB - iB * 14;
    const float* pxB = x + (b0 + imB) * 784 + (2 * iB) * 28 + 2 * jB;
    float2 rB0 = {0.f, 0.f}, rB1 = {0.f, 0.f};
    if (hasB) { rB0 = *(const float2*)(pxB); rB1 = *(const float2*)(pxB + 28); }

    // ---- Small weight tables (VALU, overlaps the x loads) ----
    uint4* b2t = (uint4*)fftb;             // alias (see above)
    if (t < 256) {                         // conv2 B-fragment e=(c*4+dy)*16+n
        const int nn = t & 15;
        const int dy = (t >> 4) & 3;
        const int cc = t >> 6;
        const int o  = nn >> 1;
        unsigned d[4];
        #pragma unroll
        for (int dx = 0; dx < 4; ++dx) {
            float a = w2[o * 64 + cc * 16 + dy * 4 + dx];
            float ss, cw;
            __sincosf(a, &ss, &cw);
            d[dx] = (nn & 1) ? packh2(-ss, cw) : packh2(cw, ss);
        }
        b2t[t] = make_uint4(d[0], d[1], d[2], d[3]);
    }
    if (t < 16) {
        float s, c;
        __sincosf(w1[t], &s, &c);
        w1t[t] = make_uint2(packh2(c, s), packh2(-s, c));
    }
    __syncthreads();

    // B-fragments to registers (every wave loads the same 4 entries/lane).
    const int n    = lane & 15;
    const int quad = lane >> 4;
    uint4 bf0 = b2t[lane];
    uint4 bf1 = b2t[64 + lane];
    uint4 bf2 = b2t[128 + lane];
    uint4 bf3 = b2t[192 + lane];

    // ---- Stage 1: sincos + 2x2/s2 conv, 1->4 ch ----
    {
        float s0, c0, s1, c1, s2, c2, s3, c3;
        __sincosf(rA0.x, &s0, &c0);
        __sincosf(rA0.y, &s1, &c1);
        __sincosf(rA1.x, &s2, &c2);
        __sincosf(rA1.y, &s3, &c3);
        const unsigned u0 = packh2(c0, s0), u1 = packh2(c1, s1);
        const unsigned u2 = packh2(c2, s2), u3 = packh2(c3, s3);
        #pragma unroll
        for (int o = 0; o < 4; ++o) {
            const uint2 wa = w1t[o * 4 + 0], wb = w1t[o * 4 + 1];
            const uint2 wc = w1t[o * 4 + 2], wd = w1t[o * 4 + 3];
            float X = 0.f, Y = 0.f;
            X = fdot2(u0, wa.x, X); Y = fdot2(u0, wa.y, Y);
            X = fdot2(u1, wb.x, X); Y = fdot2(u1, wb.y, Y);
            X = fdot2(u2, wc.x, X); Y = fdot2(u2, wc.y, Y);
            X = fdot2(u3, wd.x, X); Y = fdot2(u3, wd.y, Y);
            const float rinv = rsqrtf(fmaxf(fmaf(X, X, Y * Y), 1e-30f));
            cs1[imA][o * 196 + pA] = packh2(X * rinv, Y * rinv);
        }
    }
    if (hasB) {
        float s0, c0, s1, c1, s2, c2, s3, c3;
        __sincosf(rB0.x, &s0, &c0);
        __sincosf(rB0.y, &s1, &c1);
        __sincosf(rB1.x, &s2, &c2);
        __sincosf(rB1.y, &s3, &c3);
        const unsigned u0 = packh2(c0, s0), u1 = packh2(c1, s1);
        const unsigned u2 = packh2(c2, s2), u3 = packh2(c3, s3);
        #pragma unroll
        for (int o = 0; o < 4; ++o) {
            const uint2 wa = w1t[o * 4 + 0], wb = w1t[o * 4 + 1];
            const uint2 wc = w1t[o * 4 + 2], wd = w1t[o * 4 + 3];
            float X = 0.f, Y = 0.f;
            X = fdot2(u0, wa.x, X); Y = fdot2(u0, wa.y, Y);
            X = fdot2(u1, wb.x, X); Y = fdot2(u1, wb.y, Y);
            X = fdot2(u2, wc.x, X); Y = fdot2(u2, wc.y, Y);
            X = fdot2(u3, wd.x, X); Y = fdot2(u3, wd.y, Y);
            const float rinv = rsqrtf(fmaxf(fmaf(X, X, Y * Y), 1e-30f));
            cs1[imB][o * 196 + pB] = packh2(X * rinv, Y * rinv);
        }
    }
    __syncthreads();   // cs1 ready; all b2t register reads complete

    // ---- Stage 2: MFMA. 144 positions (4 imgs x 36) = 9 tiles of 16 ----
    const unsigned* c1 = &cs1[0][0];
    for (int tile = wave; tile < 9; tile += 8) {
        const int p  = tile * 16 + n;              // 0..143, all valid
        const int im = p / 36;
        const int ps = p - im * 36;
        const int i  = ps / 6;
        const int j  = ps - i * 6;
        const unsigned base = (unsigned)(im * 784 + (2 * i + quad) * 14 + 2 * j);
        f4 acc = {0.f, 0.f, 0.f, 0.f};
        #pragma unroll
        for (int c = 0; c < 4; ++c) {
            uint2 lo = *(const uint2*)(c1 + base + c * 196);
            uint2 hi = *(const uint2*)(c1 + base + c * 196 + 2);
            uint4 a4 = make_uint4(lo.x, lo.y, hi.x, hi.y);
            v8h av = __builtin_bit_cast(v8h, a4);
            v8h bv = __builtin_bit_cast(v8h, (c == 0) ? bf0 : (c == 1) ? bf1
                                              : (c == 2) ? bf2 : bf3);
            acc = __builtin_amdgcn_mfma_f32_16x16x32_f16(av, bv, acc, 0, 0, 0);
        }
        float pr0 = __shfl_xor(acc[0], 1);
        float pr1 = __shfl_xor(acc[1], 1);
        float pr2 = __shfl_xor(acc[2], 1);
        float pr3 = __shfl_xor(acc[3], 1);
        if (!(n & 1)) {
            const int o = n >> 1;
            float Xs[4] = {acc[0], acc[1], acc[2], acc[3]};
            float Ys[4] = {pr0, pr1, pr2, pr3};
            #pragma unroll
            for (int r = 0; r < 4; ++r) {
                const int p2  = tile * 16 + quad * 4 + r;   // 0..143
                const int im2 = p2 / 36;
                const int ps2 = p2 - im2 * 36;
                float X = Xs[r], Y = Ys[r];
                float rinv = rsqrtf(fmaxf(fmaf(X, X, Y * Y), 1e-30f));
                cs2[im2][ps2 * 8 + o] = packh2(X * rinv, Y * rinv);
            }
        }
    }
    // ff table build: overlaps stage-2 latency; writes over the consumed b2t
    // alias region (safe: past the stage-1 barrier).
    for (int e = t; e < 2880; e += 512) {
        float ss, cw;
        __sincosf(ffw[e], &ss, &cw);
        fftb[e] = packh2(cw, ss);
    }
    __syncthreads();   // cs2 + fftb ready

    // ---- Stage 3: ring-FF 288 -> 10; two independent 12-iter chains ----
    {
        const int img3 = wave >> 1;              // 0..3
        const int half = wave & 1;
        const int nl   = lane / 12;              // 0..4 active
        const int g    = lane - nl * 12;
        float XA = 0.f, YA = 0.f, XB = 0.f, YB = 0.f;
        if (nl < 5) {
            const int n3 = half * 5 + nl;
            #pragma unroll 6
            for (int k = 0; k < 12; ++k) {
                const int fA = g + 12 * k;       // features 0..143
                const int fB = fA + 144;         // features 144..287
                unsigned va = cs2[img3][fA];
                unsigned vb = cs2[img3][fB];
                unsigned ua = fftb[fA * 10 + n3];
                unsigned ub = fftb[fB * 10 + n3];
                XA = fdot2(va, ua, XA);
                YA = fdot2(va, yrot(ua), YA);
                XB = fdot2(vb, ub, XB);
                YB = fdot2(vb, yrot(ub), YB);
            }
        }
        float X = XA + XB, Y = YA + YB;
        float qX = X + __shfl_down(X, 4) + __shfl_down(X, 8);
        float qY = Y + __shfl_down(Y, 4) + __shfl_down(Y, 8);
        float sX = qX + __shfl_down(qX, 1) + __shfl_down(qX, 2) + __shfl_down(qX, 3);
        float sY = qY + __shfl_down(qY, 1) + __shfl_down(qY, 2) + __shfl_down(qY, 3);
        if (g == 0 && nl < 5) {
            const int n3 = half * 5 + nl;
            float rinv = rsqrtf(fmaxf(fmaf(sX, sX, sY * sY), 1e-30f));
            out[(b0 + img3) * 10 + n3] = sY * rinv;
        }
    }
}

extern "C" void kernel_launch(void* const* d_in, const int* in_sizes, int n_in,
                              void* d_out, int out_size, void* d_ws, size_t ws_size,
                              hipStream_t stream) {
    const float* x   = (const float*)d_in[0];
    const float* w1  = (const float*)d_in[1];
    const float* w2  = (const float*)d_in[2];
    const float* ffw = (const float*)d_in[3];
    (void)d_ws; (void)ws_size;
    ringnn_fused<<<1024, 512, 0, stream>>>(x, w1, w2, ffw, (float*)d_out);
}